// Round 1
// baseline (216.371 us; speedup 1.0000x reference)
//
#include <hip/hip_runtime.h>

// ---------------------------------------------------------------------------
// AttentionDecoder: B=64, S=512, H=1024, V=32000
// outputs (f32, concat): output [64,32000] | h_new [64,1024] | attn_w [64,512]
// ---------------------------------------------------------------------------

typedef __bf16 bf16;
typedef __attribute__((ext_vector_type(4))) float  f32x4;
typedef __attribute__((ext_vector_type(4))) float  fx4;
typedef __attribute__((ext_vector_type(8))) bf16   bf16x8;
typedef __attribute__((ext_vector_type(4))) bf16   bf16x4;
typedef __attribute__((ext_vector_type(4))) unsigned int u32x4;

#define MFMA16x16x32(a, b, c) __builtin_amdgcn_mfma_f32_16x16x32_bf16(a, b, c, 0, 0, 0)

#define Bb   64
#define Ss   512
#define Hh   1024
#define Vv   32000
#define Mtot (Bb * Ss)          // 32768

// ---- d_ws layout (bytes) --------------------------------------------------
#define WS_HPREV_B   0                       // 64*1024 bf16   = 128KB
#define WS_HNEW_B    131072                  // 64*1024 bf16   = 128KB
#define WS_XC_B      262144                  // 64*2048 bf16   = 256KB
#define WS_W1A_B     524288                  // 1024*1024 bf16 = 2MB
#define WS_P_HB      2621440                 // [4][64][1024] f32 = 1MB
#define WS_P_HZ      3670016
#define WS_P_HN      4718592
#define WS_P_IZ      5767168
#define WS_P_IR      6815744
#define WS_P_IN      7864320
#define WS_SCORES    8912896                 // [16][32768] f32 = 2MB
#define WS_CTX       11010048                // [2][64][1024] f32 = 512KB
// total ~11.6MB

// ---- d_out offsets (floats) ----------------------------------------------
#define OUT_LOGITS   0
#define OUT_HNEW     2048000
#define OUT_AW       2113536

// ===========================================================================
// k_prep: h_prev -> bf16 ; embed gather -> xc_b[:,H:2H] ; W1a -> bf16
// grid 1088 x 256
// ===========================================================================
__global__ void k_prep(const int* __restrict__ x, const float* __restrict__ h_prev,
                       const float* __restrict__ emb, const float* __restrict__ attn_W1,
                       bf16* __restrict__ h_prev_b, bf16* __restrict__ xc_b,
                       bf16* __restrict__ W1a_b)
{
    int bid = blockIdx.x, t = threadIdx.x;
    if (bid < 64) {
        int b = bid;
        int row = x[b];
        for (int i = t; i < Hh; i += 256) {
            h_prev_b[b * Hh + i]          = (bf16)h_prev[b * Hh + i];
            xc_b[b * 2048 + Hh + i]       = (bf16)emb[(size_t)row * Hh + i];
        }
    } else {
        int row = bid - 64;                  // 0..1023 (one W1a row per block)
        int k4 = t * 4;
        fx4 v = *(const fx4*)(attn_W1 + (size_t)row * 2048 + k4);
        bf16x4 o;
#pragma unroll
        for (int q = 0; q < 4; q++) o[q] = (bf16)v[q];
        *(bf16x4*)(W1a_b + (size_t)row * Hh + k4) = o;
    }
}

// ===========================================================================
// k_sgemm: M=64 GEMM, out[m][n] = sum_k A_bf16[m][k] * (f32)Bmat[n][k]
// tile BM=64 BN=64 BK=64, 4 waves (wave w: n = n0+w*16..+16), dbuf reg-staged.
// grid (N/64, nsplitk, nmat); partial out [sk][64][N] or final (+bias).
// ===========================================================================
__global__ __launch_bounds__(256, 2) void k_sgemm(
    const bf16* __restrict__ A, int lda, int kchunk,
    const float* __restrict__ B0, const float* __restrict__ B1, const float* __restrict__ B2,
    int ldb0, int ldb1, int ldb2,
    float* __restrict__ o0, float* __restrict__ o1, float* __restrict__ o2,
    const float* __restrict__ bias, int N, int finalOut)
{
    __shared__ __align__(16) bf16 lA[2][64][72];   // 144B rows: bank-safe
    __shared__ __align__(16) bf16 lB[2][64][72];

    int nb = blockIdx.x, sk = blockIdx.y, mat = blockIdx.z;
    const float* Bp = (mat == 0) ? B0 : (mat == 1 ? B1 : B2);
    int ldb         = (mat == 0) ? ldb0 : (mat == 1 ? ldb1 : ldb2);
    float* op       = (mat == 0) ? o0 : (mat == 1 ? o1 : o2);

    int n0 = nb * 64, k0 = sk * kchunk;
    int t = threadIdx.x, lane = t & 63, wid = t >> 6;
    int srow = t >> 2, schunk = t & 3;

    const bf16*  agp = A  + (size_t)srow * lda + k0 + schunk * 16;
    const float* bgp = Bp + (size_t)(n0 + srow) * ldb + k0 + schunk * 16;

    f32x4 acc[4];
#pragma unroll
    for (int i = 0; i < 4; i++) acc[i] = (f32x4)0.0f;

    u32x4 aR0, aR1; fx4 bRf[4];
    int nk = kchunk >> 6;

    // prologue
    aR0 = *(const u32x4*)(agp);
    aR1 = *(const u32x4*)(agp + 8);
#pragma unroll
    for (int q = 0; q < 4; q++) bRf[q] = *(const fx4*)(bgp + q * 4);
    {
        *(u32x4*)&lA[0][srow][schunk * 16]     = aR0;
        *(u32x4*)&lA[0][srow][schunk * 16 + 8] = aR1;
        bf16x8 p0, p1;
#pragma unroll
        for (int q = 0; q < 4; q++) {
            p0[q] = (bf16)bRf[0][q]; p0[q + 4] = (bf16)bRf[1][q];
            p1[q] = (bf16)bRf[2][q]; p1[q + 4] = (bf16)bRf[3][q];
        }
        *(bf16x8*)&lB[0][srow][schunk * 16]     = p0;
        *(bf16x8*)&lB[0][srow][schunk * 16 + 8] = p1;
    }
    __syncthreads();

    int cur = 0;
    for (int ks = 0; ks < nk; ks++) {
        if (ks + 1 < nk) {
            aR0 = *(const u32x4*)(agp + (ks + 1) * 64);
            aR1 = *(const u32x4*)(agp + (ks + 1) * 64 + 8);
#pragma unroll
            for (int q = 0; q < 4; q++) bRf[q] = *(const fx4*)(bgp + (ks + 1) * 64 + q * 4);
        }
        int rA = lane & 15;
        int kc = (lane >> 4) * 8;
#pragma unroll
        for (int kk = 0; kk < 2; kk++) {
            bf16x8 bfr = *(bf16x8*)&lB[cur][wid * 16 + rA][kk * 32 + kc];
#pragma unroll
            for (int i = 0; i < 4; i++) {
                bf16x8 af = *(bf16x8*)&lA[cur][i * 16 + rA][kk * 32 + kc];
                acc[i] = MFMA16x16x32(af, bfr, acc[i]);
            }
        }
        if (ks + 1 < nk) {
            int nxt = cur ^ 1;
            *(u32x4*)&lA[nxt][srow][schunk * 16]     = aR0;
            *(u32x4*)&lA[nxt][srow][schunk * 16 + 8] = aR1;
            bf16x8 p0, p1;
#pragma unroll
            for (int q = 0; q < 4; q++) {
                p0[q] = (bf16)bRf[0][q]; p0[q + 4] = (bf16)bRf[1][q];
                p1[q] = (bf16)bRf[2][q]; p1[q + 4] = (bf16)bRf[3][q];
            }
            *(bf16x8*)&lB[nxt][srow][schunk * 16]     = p0;
            *(bf16x8*)&lB[nxt][srow][schunk * 16 + 8] = p1;
        }
        __syncthreads();
        cur ^= 1;
    }

    int n = n0 + wid * 16 + (lane & 15);
#pragma unroll
    for (int i = 0; i < 4; i++) {
#pragma unroll
        for (int r = 0; r < 4; r++) {
            int m = i * 16 + (lane >> 4) * 4 + r;
            float v = acc[i][r];
            if (finalOut) op[(size_t)m * N + n] = v + bias[n];
            else          op[(size_t)(sk * 64 + m) * N + n] = v;
        }
    }
}

// ===========================================================================
// k_attn: scores_part[nb*2+wn][m] = sum over 128-n-slice of
//         relu(ann@W1a^T + hB + b1) * W2      (fused epilogue, no hidden_act)
// M=32768, N=1024, K=1024. BM=BN=128, BK=32, 4 waves (2x2, 64x64 each).
// grid 2048 x 256. XCD-swizzled so each XCD sweeps 32 consecutive m-panels.
// ===========================================================================
__global__ __launch_bounds__(256, 2) void k_attn(
    const float* __restrict__ ann, const bf16* __restrict__ Bw,
    const float* __restrict__ p_hB, const float* __restrict__ b1,
    const float* __restrict__ W2, float* __restrict__ scores_part)
{
    __shared__ __align__(16) bf16 ldsA[2][128][40];   // 80B rows: 2-way banks = free
    __shared__ __align__(16) bf16 ldsB[2][128][40];

    int bid = blockIdx.x;
    int swz = (bid & 7) * 256 + (bid >> 3);
    int mb = swz >> 3, nb = swz & 7;

    int t = threadIdx.x;
    int lane = t & 63, wid = t >> 6;
    int wm = wid >> 1, wn = wid & 1;

    int arow = t >> 1, ahalf = t & 1;                 // 128 rows x 2 halves (16 elems)
    const float* ag = ann + (size_t)(mb * 128 + arow) * Hh + ahalf * 16;
    const bf16*  bg = Bw  + (size_t)(nb * 128 + arow) * Hh + ahalf * 16;

    f32x4 acc[4][4];
#pragma unroll
    for (int i = 0; i < 4; i++)
#pragma unroll
        for (int j = 0; j < 4; j++) acc[i][j] = (f32x4)0.0f;

    fx4 aR[4]; u32x4 bR0, bR1;

    // prologue: tile 0
#pragma unroll
    for (int q = 0; q < 4; q++) aR[q] = *(const fx4*)(ag + q * 4);
    bR0 = *(const u32x4*)(bg);
    bR1 = *(const u32x4*)(bg + 8);
    {
        bf16x8 p0, p1;
#pragma unroll
        for (int q = 0; q < 4; q++) {
            p0[q] = (bf16)aR[0][q]; p0[q + 4] = (bf16)aR[1][q];
            p1[q] = (bf16)aR[2][q]; p1[q + 4] = (bf16)aR[3][q];
        }
        *(bf16x8*)&ldsA[0][arow][ahalf * 16]     = p0;
        *(bf16x8*)&ldsA[0][arow][ahalf * 16 + 8] = p1;
        *(u32x4*)&ldsB[0][arow][ahalf * 16]      = bR0;
        *(u32x4*)&ldsB[0][arow][ahalf * 16 + 8]  = bR1;
    }
    __syncthreads();

    int cur = 0;
    for (int kt = 0; kt < 32; kt++) {
        if (kt < 31) {
            const float* ag2 = ag + (kt + 1) * 32;
            const bf16*  bg2 = bg + (kt + 1) * 32;
#pragma unroll
            for (int q = 0; q < 4; q++) aR[q] = *(const fx4*)(ag2 + q * 4);
            bR0 = *(const u32x4*)(bg2);
            bR1 = *(const u32x4*)(bg2 + 8);
        }
        // compute current tile
        {
            bf16x8 af[4], bfr[4];
            int rA = wm * 64 + (lane & 15);
            int rB = wn * 64 + (lane & 15);
            int kc = (lane >> 4) * 8;
#pragma unroll
            for (int i = 0; i < 4; i++) af[i]  = *(bf16x8*)&ldsA[cur][rA + i * 16][kc];
#pragma unroll
            for (int j = 0; j < 4; j++) bfr[j] = *(bf16x8*)&ldsB[cur][rB + j * 16][kc];
#pragma unroll
            for (int i = 0; i < 4; i++)
#pragma unroll
                for (int j = 0; j < 4; j++)
                    acc[i][j] = MFMA16x16x32(af[i], bfr[j], acc[i][j]);
        }
        if (kt < 31) {
            int nxt = cur ^ 1;
            bf16x8 p0, p1;
#pragma unroll
            for (int q = 0; q < 4; q++) {
                p0[q] = (bf16)aR[0][q]; p0[q + 4] = (bf16)aR[1][q];
                p1[q] = (bf16)aR[2][q]; p1[q + 4] = (bf16)aR[3][q];
            }
            *(bf16x8*)&ldsA[nxt][arow][ahalf * 16]     = p0;
            *(bf16x8*)&ldsA[nxt][arow][ahalf * 16 + 8] = p1;
            *(u32x4*)&ldsB[nxt][arow][ahalf * 16]      = bR0;
            *(u32x4*)&ldsB[nxt][arow][ahalf * 16 + 8]  = bR1;
        }
        __syncthreads();
        cur ^= 1;
    }

    // fused epilogue: relu(hA + hB + b1) * W2, reduce over this block's 128 n
    int m0 = mb * 128, n0 = nb * 128;
    int b = m0 >> 9;                                   // batch (uniform per block)
    float hb[4], w2v[4];
#pragma unroll
    for (int j = 0; j < 4; j++) {
        int n = n0 + wn * 64 + j * 16 + (lane & 15);
        float h = p_hB[b * Hh + n] + p_hB[65536 + b * Hh + n]
                + p_hB[131072 + b * Hh + n] + p_hB[196608 + b * Hh + n];
        hb[j]  = h + b1[n];
        w2v[j] = W2[n];
    }
    float red[16];
#pragma unroll
    for (int i = 0; i < 4; i++)
#pragma unroll
        for (int r = 0; r < 4; r++) {
            float s = 0.f;
#pragma unroll
            for (int j = 0; j < 4; j++) {
                float v = acc[i][j][r] + hb[j];
                v = fmaxf(v, 0.f);
                s += v * w2v[j];
            }
            red[i * 4 + r] = s;
        }
#pragma unroll
    for (int mask = 1; mask <= 8; mask <<= 1)
#pragma unroll
        for (int q = 0; q < 16; q++)
            red[q] += __shfl_xor(red[q], mask, 64);

    if ((lane & 15) == 0) {
        float* sp = scores_part + (size_t)(nb * 2 + wn) * Mtot + m0 + wm * 64 + (lane >> 4) * 4;
#pragma unroll
        for (int i = 0; i < 4; i++)
#pragma unroll
            for (int r = 0; r < 4; r++)
                sp[i * 16 + r] = red[i * 4 + r];
    }
}

// ===========================================================================
// k_softmax: per b (64 blocks x 512 thr): sum 16 partials, softmax over s.
// ===========================================================================
__global__ void k_softmax(const float* __restrict__ scores_part, float* __restrict__ aw)
{
    int b = blockIdx.x, s = threadIdx.x;
    int lane = s & 63, wid = s >> 6;
    float v = 0.f;
#pragma unroll
    for (int p = 0; p < 16; p++) v += scores_part[(size_t)p * Mtot + b * Ss + s];

    __shared__ float redm[8], redsum[8];
    float m = v;
#pragma unroll
    for (int mask = 32; mask; mask >>= 1) m = fmaxf(m, __shfl_xor(m, mask, 64));
    if (lane == 0) redm[wid] = m;
    __syncthreads();
    float bm = redm[0];
#pragma unroll
    for (int w = 1; w < 8; w++) bm = fmaxf(bm, redm[w]);

    float e = expf(v - bm);
    float ss = e;
#pragma unroll
    for (int mask = 32; mask; mask >>= 1) ss += __shfl_xor(ss, mask, 64);
    if (lane == 0) redsum[wid] = ss;
    __syncthreads();
    float tot = 0.f;
#pragma unroll
    for (int w = 0; w < 8; w++) tot += redsum[w];

    aw[b * Ss + s] = e / tot;
}

// ===========================================================================
// k_context: ctx_part[sc][b][h] = sum_{s in chunk} aw[b,s]*ann[b,s,h]
// grid 512 (b*8 + ht*2 + sc) x 256
// ===========================================================================
__global__ void k_context(const float* __restrict__ ann, const float* __restrict__ aw,
                          float* __restrict__ ctx_part)
{
    __shared__ float law[256];
    int bid = blockIdx.x;
    int b = bid >> 3, ht = (bid >> 1) & 3, sc = bid & 1;
    int t = threadIdx.x;
    law[t] = aw[b * Ss + sc * 256 + t];
    __syncthreads();
    int h = ht * 256 + t;
    const float* ap = ann + (size_t)(b * Ss + sc * 256) * Hh + h;
    float acc = 0.f;
#pragma unroll 8
    for (int s2 = 0; s2 < 256; s2++) acc += law[s2] * ap[(size_t)s2 * Hh];
    ctx_part[sc * 65536 + b * Hh + h] = acc;
}

// ===========================================================================
// k_xc: xc_b[:, 0:H] = bf16(ctx_part[0] + ctx_part[1])
// ===========================================================================
__global__ void k_xc(const float* __restrict__ ctx_part, bf16* __restrict__ xc_b)
{
    int idx = blockIdx.x * 256 + threadIdx.x;          // 65536
    float c = ctx_part[idx] + ctx_part[65536 + idx];
    int b = idx >> 10, h = idx & 1023;
    xc_b[b * 2048 + h] = (bf16)c;
}

// ===========================================================================
// k_gru: gates + h_new (reads 4-way split-K partials)
// ===========================================================================
__global__ void k_gru(const float* __restrict__ p_iz, const float* __restrict__ p_ir,
                      const float* __restrict__ p_in, const float* __restrict__ p_hz,
                      const float* __restrict__ p_hn,
                      const float* __restrict__ b_iz, const float* __restrict__ b_ir,
                      const float* __restrict__ b_in, const float* __restrict__ b_hz,
                      const float* __restrict__ b_hn,
                      const float* __restrict__ h_prev,
                      float* __restrict__ out_h, bf16* __restrict__ h_new_b)
{
    int idx = blockIdx.x * 256 + threadIdx.x;          // 65536
    int o = idx & 1023;
    float iz = p_iz[idx] + p_iz[65536 + idx] + p_iz[131072 + idx] + p_iz[196608 + idx];
    float ir = p_ir[idx] + p_ir[65536 + idx] + p_ir[131072 + idx] + p_ir[196608 + idx];
    float in_ = p_in[idx] + p_in[65536 + idx] + p_in[131072 + idx] + p_in[196608 + idx];
    float hz = p_hz[idx] + p_hz[65536 + idx] + p_hz[131072 + idx] + p_hz[196608 + idx];
    float hn = p_hn[idx] + p_hn[65536 + idx] + p_hn[131072 + idx] + p_hn[196608 + idx];
    hz += b_hz[o];
    hn += b_hn[o];
    float z = 1.f / (1.f + expf(-(iz + b_iz[o] + hz)));
    float r = 1.f / (1.f + expf(-(ir + b_ir[o] + hz)));
    float g = tanhf(in_ + b_in[o] + r * hn);
    float hp = h_prev[idx];
    float hnew = (1.f - z) * g + z * hp;
    out_h[idx] = hnew;
    h_new_b[idx] = (bf16)hnew;
}

// ===========================================================================
extern "C" void kernel_launch(void* const* d_in, const int* in_sizes, int n_in,
                              void* d_out, int out_size, void* d_ws, size_t ws_size,
                              hipStream_t stream)
{
    const int*   x        = (const int*)d_in[0];
    const float* h_prev   = (const float*)d_in[1];
    const float* ann      = (const float*)d_in[2];
    const float* emb      = (const float*)d_in[3];
    const float* attn_W1  = (const float*)d_in[4];
    const float* attn_b1  = (const float*)d_in[5];
    const float* attn_W2  = (const float*)d_in[6];
    const float* W_ir     = (const float*)d_in[8];
    const float* b_ir     = (const float*)d_in[9];
    const float* W_iz     = (const float*)d_in[10];
    const float* b_iz     = (const float*)d_in[11];
    const float* W_in     = (const float*)d_in[12];
    const float* b_in     = (const float*)d_in[13];
    const float* W_hz     = (const float*)d_in[14];
    const float* b_hz     = (const float*)d_in[15];
    const float* W_hn     = (const float*)d_in[16];
    const float* b_hn     = (const float*)d_in[17];
    const float* W_out    = (const float*)d_in[18];
    const float* b_out    = (const float*)d_in[19];

    float* out = (float*)d_out;
    char*  ws  = (char*)d_ws;

    bf16*  h_prev_b = (bf16*)(ws + WS_HPREV_B);
    bf16*  h_new_b  = (bf16*)(ws + WS_HNEW_B);
    bf16*  xc_b     = (bf16*)(ws + WS_XC_B);
    bf16*  W1a_b    = (bf16*)(ws + WS_W1A_B);
    float* p_hB     = (float*)(ws + WS_P_HB);
    float* p_hz     = (float*)(ws + WS_P_HZ);
    float* p_hn     = (float*)(ws + WS_P_HN);
    float* p_iz     = (float*)(ws + WS_P_IZ);
    float* p_ir     = (float*)(ws + WS_P_IR);
    float* p_in     = (float*)(ws + WS_P_IN);
    float* scores_p = (float*)(ws + WS_SCORES);
    float* ctx_part = (float*)(ws + WS_CTX);

    // 1) conversions + embedding gather
    k_prep<<<1088, 256, 0, stream>>>(x, h_prev, emb, attn_W1, h_prev_b, xc_b, W1a_b);

    // 2) hB / hz / hn  (h_prev @ {W1b, W_hz, W_hn}^T), split-K=4 partials
    {
        dim3 g(16, 4, 3);
        k_sgemm<<<g, 256, 0, stream>>>(h_prev_b, 1024, 256,
                                       attn_W1 + 1024, W_hz, W_hn, 2048, 1024, 1024,
                                       p_hB, p_hz, p_hn, nullptr, 1024, 0);
    }

    // 3) fused attention GEMM -> 16 score partials
    k_attn<<<2048, 256, 0, stream>>>(ann, W1a_b, p_hB, attn_b1, attn_W2, scores_p);

    // 4) softmax -> attention weights (final output region)
    k_softmax<<<64, 512, 0, stream>>>(scores_p, out + OUT_AW);

    // 5) context = sum_s aw * ann  (2 s-chunks)
    k_context<<<512, 256, 0, stream>>>(ann, out + OUT_AW, ctx_part);

    // 6) xc = [context, embed] in bf16
    k_xc<<<256, 256, 0, stream>>>(ctx_part, xc_b);

    // 7) gate GEMMs (xc @ {W_iz, W_ir, W_in}^T), K=2048, split-K=4
    {
        dim3 g(16, 4, 3);
        k_sgemm<<<g, 256, 0, stream>>>(xc_b, 2048, 512,
                                       W_iz, W_ir, W_in, 2048, 2048, 2048,
                                       p_iz, p_ir, p_in, nullptr, 1024, 0);
    }

    // 8) GRU elementwise -> h_new (f32 out + bf16 ws)
    k_gru<<<256, 256, 0, stream>>>(p_iz, p_ir, p_in, p_hz, p_hn,
                                   b_iz, b_ir, b_in, b_hz, b_hn,
                                   h_prev, out + OUT_HNEW, h_new_b);

    // 9) output logits = h_new @ W_out^T + b_out
    {
        dim3 g(500, 1, 1);
        k_sgemm<<<g, 256, 0, stream>>>(h_new_b, 1024, 1024,
                                       W_out, W_out, W_out, 1024, 1024, 1024,
                                       out + OUT_LOGITS, nullptr, nullptr,
                                       b_out, 32000, 1);
    }
}

// Round 2
// 185.970 us; speedup vs baseline: 1.1635x; 1.1635x over previous
//
#include <hip/hip_runtime.h>

// ---------------------------------------------------------------------------
// AttentionDecoder: B=64, S=512, H=1024, V=32000
// outputs (f32, concat): output [64,32000] | h_new [64,1024] | attn_w [64,512]
// ---------------------------------------------------------------------------

typedef __bf16 bf16;
typedef __attribute__((ext_vector_type(4))) float  f32x4;
typedef __attribute__((ext_vector_type(4))) float  fx4;
typedef __attribute__((ext_vector_type(8))) bf16   bf16x8;
typedef __attribute__((ext_vector_type(4))) bf16   bf16x4;
typedef __attribute__((ext_vector_type(4))) unsigned int u32x4;
typedef __attribute__((ext_vector_type(2))) unsigned int u32x2;

#define MFMA16x16x32(a, b, c) __builtin_amdgcn_mfma_f32_16x16x32_bf16(a, b, c, 0, 0, 0)

#define Bb   64
#define Ss   512
#define Hh   1024
#define Vv   32000
#define Mtot (Bb * Ss)          // 32768

// ---- d_ws layout (bytes) --------------------------------------------------
#define WS_HPREV_B   0                       // 64*1024 bf16   = 128KB
#define WS_HNEW_B    131072                  // 64*1024 bf16   = 128KB
#define WS_XC_B      262144                  // 64*2048 bf16   = 256KB
#define WS_W1A_B     524288                  // 1024*1024 bf16 = 2MB
#define WS_P_HB      2621440                 // [4][64][1024] f32 = 1MB
#define WS_P_HZ      3670016
#define WS_P_HN      4718592
#define WS_P_IZ      5767168
#define WS_P_IR      6815744
#define WS_P_IN      7864320
#define WS_SCORES    8912896                 // [16][32768] f32 = 2MB
#define WS_CTX       11010048                // [8][64][1024] f32 = 2MB
#define WS_ANNB      13107200                // 32768*1024 bf16 = 64MB
// total ~80.3MB

// ---- d_out offsets (floats) ----------------------------------------------
#define OUT_LOGITS   0
#define OUT_HNEW     2048000
#define OUT_AW       2113536

__device__ __forceinline__ float bf2f(unsigned short u) {
    unsigned int x = ((unsigned int)u) << 16;
    float f;
    __builtin_memcpy(&f, &x, 4);
    return f;
}

// async global->LDS, 16B per lane. LDS dest must be wave-uniform base;
// HW writes base + lane*16.
__device__ __forceinline__ void gload_lds16(const bf16* g, bf16* l)
{
    __builtin_amdgcn_global_load_lds(
        (const __attribute__((address_space(1))) unsigned int*)g,
        (__attribute__((address_space(3))) unsigned int*)l,
        16, 0, 0);
}

// ===========================================================================
// k_prep: h_prev -> bf16 ; embed gather -> xc_b[:,H:2H] ; W1a -> bf16
// grid 1088 x 256
// ===========================================================================
__global__ void k_prep(const int* __restrict__ x, const float* __restrict__ h_prev,
                       const float* __restrict__ emb, const float* __restrict__ attn_W1,
                       bf16* __restrict__ h_prev_b, bf16* __restrict__ xc_b,
                       bf16* __restrict__ W1a_b)
{
    int bid = blockIdx.x, t = threadIdx.x;
    if (bid < 64) {
        int b = bid;
        int row = x[b];
        for (int i = t; i < Hh; i += 256) {
            h_prev_b[b * Hh + i]          = (bf16)h_prev[b * Hh + i];
            xc_b[b * 2048 + Hh + i]       = (bf16)emb[(size_t)row * Hh + i];
        }
    } else {
        int row = bid - 64;                  // 0..1023 (one W1a row per block)
        int k4 = t * 4;
        fx4 v = *(const fx4*)(attn_W1 + (size_t)row * 2048 + k4);
        bf16x4 o;
#pragma unroll
        for (int q = 0; q < 4; q++) o[q] = (bf16)v[q];
        *(bf16x4*)(W1a_b + (size_t)row * Hh + k4) = o;
    }
}

// ===========================================================================
// k_convann: ann f32 -> bf16 (grid-stride, 8 elems/thread/iter)
// ===========================================================================
__global__ void k_convann(const float* __restrict__ ann, bf16* __restrict__ annb)
{
    size_t i = ((size_t)blockIdx.x * 256 + threadIdx.x) * 8;
    size_t stride = (size_t)gridDim.x * 256 * 8;
    size_t n = (size_t)Mtot * Hh;
    for (; i < n; i += stride) {
        fx4 v0 = *(const fx4*)(ann + i);
        fx4 v1 = *(const fx4*)(ann + i + 4);
        bf16x8 o;
#pragma unroll
        for (int q = 0; q < 4; q++) { o[q] = (bf16)v0[q]; o[q + 4] = (bf16)v1[q]; }
        *(bf16x8*)(annb + i) = o;
    }
}

// ===========================================================================
// k_sgemm: M=64 GEMM, out[m][n] = sum_k A_bf16[m][k] * (f32)Bmat[n][k]
// tile BM=64 BN=64 BK=64, 4 waves, dbuf reg-staged.
// grid (N/64, nsplitk, nmat); partial out [sk][64][N] or final (+bias).
// ===========================================================================
__global__ __launch_bounds__(256, 2) void k_sgemm(
    const bf16* __restrict__ A, int lda, int kchunk,
    const float* __restrict__ B0, const float* __restrict__ B1, const float* __restrict__ B2,
    int ldb0, int ldb1, int ldb2,
    float* __restrict__ o0, float* __restrict__ o1, float* __restrict__ o2,
    const float* __restrict__ bias, int N, int finalOut)
{
    __shared__ __align__(16) bf16 lA[2][64][72];
    __shared__ __align__(16) bf16 lB[2][64][72];

    int nb = blockIdx.x, sk = blockIdx.y, mat = blockIdx.z;
    const float* Bp = (mat == 0) ? B0 : (mat == 1 ? B1 : B2);
    int ldb         = (mat == 0) ? ldb0 : (mat == 1 ? ldb1 : ldb2);
    float* op       = (mat == 0) ? o0 : (mat == 1 ? o1 : o2);

    int n0 = nb * 64, k0 = sk * kchunk;
    int t = threadIdx.x, lane = t & 63, wid = t >> 6;
    int srow = t >> 2, schunk = t & 3;

    const bf16*  agp = A  + (size_t)srow * lda + k0 + schunk * 16;
    const float* bgp = Bp + (size_t)(n0 + srow) * ldb + k0 + schunk * 16;

    f32x4 acc[4];
#pragma unroll
    for (int i = 0; i < 4; i++) acc[i] = (f32x4)0.0f;

    u32x4 aR0, aR1; fx4 bRf[4];
    int nk = kchunk >> 6;

    aR0 = *(const u32x4*)(agp);
    aR1 = *(const u32x4*)(agp + 8);
#pragma unroll
    for (int q = 0; q < 4; q++) bRf[q] = *(const fx4*)(bgp + q * 4);
    {
        *(u32x4*)&lA[0][srow][schunk * 16]     = aR0;
        *(u32x4*)&lA[0][srow][schunk * 16 + 8] = aR1;
        bf16x8 p0, p1;
#pragma unroll
        for (int q = 0; q < 4; q++) {
            p0[q] = (bf16)bRf[0][q]; p0[q + 4] = (bf16)bRf[1][q];
            p1[q] = (bf16)bRf[2][q]; p1[q + 4] = (bf16)bRf[3][q];
        }
        *(bf16x8*)&lB[0][srow][schunk * 16]     = p0;
        *(bf16x8*)&lB[0][srow][schunk * 16 + 8] = p1;
    }
    __syncthreads();

    int cur = 0;
    for (int ks = 0; ks < nk; ks++) {
        if (ks + 1 < nk) {
            aR0 = *(const u32x4*)(agp + (ks + 1) * 64);
            aR1 = *(const u32x4*)(agp + (ks + 1) * 64 + 8);
#pragma unroll
            for (int q = 0; q < 4; q++) bRf[q] = *(const fx4*)(bgp + (ks + 1) * 64 + q * 4);
        }
        int rA = lane & 15;
        int kc = (lane >> 4) * 8;
#pragma unroll
        for (int kk = 0; kk < 2; kk++) {
            bf16x8 bfr = *(bf16x8*)&lB[cur][wid * 16 + rA][kk * 32 + kc];
#pragma unroll
            for (int i = 0; i < 4; i++) {
                bf16x8 af = *(bf16x8*)&lA[cur][i * 16 + rA][kk * 32 + kc];
                acc[i] = MFMA16x16x32(af, bfr, acc[i]);
            }
        }
        if (ks + 1 < nk) {
            int nxt = cur ^ 1;
            *(u32x4*)&lA[nxt][srow][schunk * 16]     = aR0;
            *(u32x4*)&lA[nxt][srow][schunk * 16 + 8] = aR1;
            bf16x8 p0, p1;
#pragma unroll
            for (int q = 0; q < 4; q++) {
                p0[q] = (bf16)bRf[0][q]; p0[q + 4] = (bf16)bRf[1][q];
                p1[q] = (bf16)bRf[2][q]; p1[q + 4] = (bf16)bRf[3][q];
            }
            *(bf16x8*)&lB[nxt][srow][schunk * 16]     = p0;
            *(bf16x8*)&lB[nxt][srow][schunk * 16 + 8] = p1;
        }
        __syncthreads();
        cur ^= 1;
    }

    int n = n0 + wid * 16 + (lane & 15);
#pragma unroll
    for (int i = 0; i < 4; i++) {
#pragma unroll
        for (int r = 0; r < 4; r++) {
            int m = i * 16 + (lane >> 4) * 4 + r;
            float v = acc[i][r];
            if (finalOut) op[(size_t)m * N + n] = v + bias[n];
            else          op[(size_t)(sk * 64 + m) * N + n] = v;
        }
    }
}

// ===========================================================================
// k_attn v2 (m97 structure): bf16 A/B, global_load_lds staging, BK=32,
// both-sides XOR chunk-swizzle (chunk ^= (row>>1)&3) -> 2-way bank access.
// scores_part[nb*2+wn][m] = sum over 128-n-slice of relu(hA+hB+b1)*W2.
// grid 2048 x 256, XCD-swizzled.
// ===========================================================================
__global__ __launch_bounds__(256, 4) void k_attn(
    const bf16* __restrict__ annb, const bf16* __restrict__ Bw,
    const float* __restrict__ p_hB, const float* __restrict__ b1,
    const float* __restrict__ W2, float* __restrict__ scores_part)
{
    __shared__ __align__(16) bf16 lA[2][4096];   // [128 rows][32 k] linear
    __shared__ __align__(16) bf16 lB[2][4096];

    int bid = blockIdx.x;
    int swz = (bid & 7) * 256 + (bid >> 3);
    int mb = swz >> 3, nb = swz & 7;

    int t = threadIdx.x, lane = t & 63, wid = t >> 6;
    int wm = wid >> 1, wn = wid & 1;

    // staging: thread t covers 16B chunk (row = t>>2 [+64], chunk = t&3).
    // source chunk pre-swizzled: gch = sch ^ ((row>>1)&3)  (involution)
    int srow = t >> 2, sch = t & 3;
    int row1 = srow + 64;
    int g0 = (sch ^ ((srow >> 1) & 3)) << 3;     // bf16 elems
    int g1 = (sch ^ ((row1 >> 1) & 3)) << 3;
    const bf16* aS0 = annb + (size_t)(mb * 128 + srow) * 1024 + g0;
    const bf16* aS1 = annb + (size_t)(mb * 128 + row1) * 1024 + g1;
    const bf16* bS0 = Bw   + (size_t)(nb * 128 + srow) * 1024 + g0;
    const bf16* bS1 = Bw   + (size_t)(nb * 128 + row1) * 1024 + g1;
    int lo0 = wid * 512;            // wave-uniform LDS dest (bf16 elems)
    int lo1 = 2048 + wid * 512;

#define STAGE(buf, kt) do { \
        gload_lds16(aS0 + (size_t)(kt) * 32, &lA[buf][lo0]); \
        gload_lds16(aS1 + (size_t)(kt) * 32, &lA[buf][lo1]); \
        gload_lds16(bS0 + (size_t)(kt) * 32, &lB[buf][lo0]); \
        gload_lds16(bS1 + (size_t)(kt) * 32, &lB[buf][lo1]); \
    } while (0)

    f32x4 acc[4][4];
#pragma unroll
    for (int i = 0; i < 4; i++)
#pragma unroll
        for (int j = 0; j < 4; j++) acc[i][j] = (f32x4)0.0f;

    STAGE(0, 0);
    __syncthreads();                // compiler drains vmcnt(0) before barrier

    int r = lane & 15, q = lane >> 4;
    int cur = 0;
    for (int kt = 0; kt < 32; kt++) {
        if (kt < 31) STAGE(cur ^ 1, kt + 1);

        bf16x8 af[4], bfr[4];
#pragma unroll
        for (int i = 0; i < 4; i++) {
            int rA = wm * 64 + i * 16 + r;
            af[i] = *(const bf16x8*)&lA[cur][rA * 32 + ((q ^ ((rA >> 1) & 3)) << 3)];
        }
#pragma unroll
        for (int j = 0; j < 4; j++) {
            int rB = wn * 64 + j * 16 + r;
            bfr[j] = *(const bf16x8*)&lB[cur][rB * 32 + ((q ^ ((rB >> 1) & 3)) << 3)];
        }
#pragma unroll
        for (int i = 0; i < 4; i++)
#pragma unroll
            for (int j = 0; j < 4; j++)
                acc[i][j] = MFMA16x16x32(af[i], bfr[j], acc[i][j]);

        __syncthreads();
        cur ^= 1;
    }
#undef STAGE

    // fused epilogue: relu(hA + hB + b1) * W2, reduce over this block's 128 n
    int m0 = mb * 128, n0 = nb * 128;
    int b = m0 >> 9;
    float hb[4], w2v[4];
#pragma unroll
    for (int j = 0; j < 4; j++) {
        int n = n0 + wn * 64 + j * 16 + r;
        float h = p_hB[b * Hh + n] + p_hB[65536 + b * Hh + n]
                + p_hB[131072 + b * Hh + n] + p_hB[196608 + b * Hh + n];
        hb[j]  = h + b1[n];
        w2v[j] = W2[n];
    }
    float red[16];
#pragma unroll
    for (int i = 0; i < 4; i++)
#pragma unroll
        for (int rr = 0; rr < 4; rr++) {
            float s = 0.f;
#pragma unroll
            for (int j = 0; j < 4; j++) {
                float v = acc[i][j][rr] + hb[j];
                v = fmaxf(v, 0.f);
                s += v * w2v[j];
            }
            red[i * 4 + rr] = s;
        }
#pragma unroll
    for (int mask = 1; mask <= 8; mask <<= 1)
#pragma unroll
        for (int p = 0; p < 16; p++)
            red[p] += __shfl_xor(red[p], mask, 64);

    if (r == 0) {
        float* sp = scores_part + (size_t)(nb * 2 + wn) * Mtot + m0 + wm * 64 + q * 4;
#pragma unroll
        for (int i = 0; i < 4; i++)
#pragma unroll
            for (int rr = 0; rr < 4; rr++)
                sp[i * 16 + rr] = red[i * 4 + rr];
    }
}

// ===========================================================================
// k_softmax: per b (64 blocks x 512 thr): sum 16 partials, softmax over s.
// ===========================================================================
__global__ void k_softmax(const float* __restrict__ scores_part, float* __restrict__ aw)
{
    int b = blockIdx.x, s = threadIdx.x;
    int lane = s & 63, wid = s >> 6;
    float v = 0.f;
#pragma unroll
    for (int p = 0; p < 16; p++) v += scores_part[(size_t)p * Mtot + b * Ss + s];

    __shared__ float redm[8], redsum[8];
    float m = v;
#pragma unroll
    for (int mask = 32; mask; mask >>= 1) m = fmaxf(m, __shfl_xor(m, mask, 64));
    if (lane == 0) redm[wid] = m;
    __syncthreads();
    float bm = redm[0];
#pragma unroll
    for (int w = 1; w < 8; w++) bm = fmaxf(bm, redm[w]);

    float e = expf(v - bm);
    float ss = e;
#pragma unroll
    for (int mask = 32; mask; mask >>= 1) ss += __shfl_xor(ss, mask, 64);
    if (lane == 0) redsum[wid] = ss;
    __syncthreads();
    float tot = 0.f;
#pragma unroll
    for (int w = 0; w < 8; w++) tot += redsum[w];

    aw[b * Ss + s] = e / tot;
}

// ===========================================================================
// k_context: ctx_part[sc][b][h] = sum_{s in 64-chunk} aw[b,s]*annb[b,s,h]
// grid 512 (b*8+sc) x 256 ; each thread 4 h's, 8B bf16 loads.
// ===========================================================================
__global__ void k_context(const bf16* __restrict__ annb, const float* __restrict__ aw,
                          float* __restrict__ ctx_part)
{
    __shared__ float law[64];
    int bid = blockIdx.x;
    int b = bid >> 3, sc = bid & 7;
    int t = threadIdx.x;
    if (t < 64) law[t] = aw[b * Ss + sc * 64 + t];
    __syncthreads();
    int h0 = t * 4;
    const bf16* ap = annb + (size_t)(b * Ss + sc * 64) * Hh + h0;
    float a0 = 0, a1 = 0, a2 = 0, a3 = 0;
#pragma unroll 4
    for (int s2 = 0; s2 < 64; s2++) {
        float w = law[s2];
        u32x2 v = *(const u32x2*)(ap + (size_t)s2 * Hh);
        a0 += w * bf2f((unsigned short)(v[0] & 0xffff));
        a1 += w * bf2f((unsigned short)(v[0] >> 16));
        a2 += w * bf2f((unsigned short)(v[1] & 0xffff));
        a3 += w * bf2f((unsigned short)(v[1] >> 16));
    }
    fx4 o; o[0] = a0; o[1] = a1; o[2] = a2; o[3] = a3;
    *(fx4*)(ctx_part + sc * 65536 + b * Hh + h0) = o;
}

// ===========================================================================
// k_xc: xc_b[:, 0:H] = bf16(sum of 8 ctx partials)
// ===========================================================================
__global__ void k_xc(const float* __restrict__ ctx_part, bf16* __restrict__ xc_b)
{
    int idx = blockIdx.x * 256 + threadIdx.x;          // 65536
    float c = 0.f;
#pragma unroll
    for (int p = 0; p < 8; p++) c += ctx_part[p * 65536 + idx];
    int b = idx >> 10, h = idx & 1023;
    xc_b[b * 2048 + h] = (bf16)c;
}

// ===========================================================================
// k_gru: gates + h_new (reads 4-way split-K partials)
// ===========================================================================
__global__ void k_gru(const float* __restrict__ p_iz, const float* __restrict__ p_ir,
                      const float* __restrict__ p_in, const float* __restrict__ p_hz,
                      const float* __restrict__ p_hn,
                      const float* __restrict__ b_iz, const float* __restrict__ b_ir,
                      const float* __restrict__ b_in, const float* __restrict__ b_hz,
                      const float* __restrict__ b_hn,
                      const float* __restrict__ h_prev,
                      float* __restrict__ out_h, bf16* __restrict__ h_new_b)
{
    int idx = blockIdx.x * 256 + threadIdx.x;          // 65536
    int o = idx & 1023;
    float iz = p_iz[idx] + p_iz[65536 + idx] + p_iz[131072 + idx] + p_iz[196608 + idx];
    float ir = p_ir[idx] + p_ir[65536 + idx] + p_ir[131072 + idx] + p_ir[196608 + idx];
    float in_ = p_in[idx] + p_in[65536 + idx] + p_in[131072 + idx] + p_in[196608 + idx];
    float hz = p_hz[idx] + p_hz[65536 + idx] + p_hz[131072 + idx] + p_hz[196608 + idx];
    float hn = p_hn[idx] + p_hn[65536 + idx] + p_hn[131072 + idx] + p_hn[196608 + idx];
    hz += b_hz[o];
    hn += b_hn[o];
    float z = 1.f / (1.f + expf(-(iz + b_iz[o] + hz)));
    float r = 1.f / (1.f + expf(-(ir + b_ir[o] + hz)));
    float g = tanhf(in_ + b_in[o] + r * hn);
    float hp = h_prev[idx];
    float hnew = (1.f - z) * g + z * hp;
    out_h[idx] = hnew;
    h_new_b[idx] = (bf16)hnew;
}

// ===========================================================================
extern "C" void kernel_launch(void* const* d_in, const int* in_sizes, int n_in,
                              void* d_out, int out_size, void* d_ws, size_t ws_size,
                              hipStream_t stream)
{
    const int*   x        = (const int*)d_in[0];
    const float* h_prev   = (const float*)d_in[1];
    const float* ann      = (const float*)d_in[2];
    const float* emb      = (const float*)d_in[3];
    const float* attn_W1  = (const float*)d_in[4];
    const float* attn_b1  = (const float*)d_in[5];
    const float* attn_W2  = (const float*)d_in[6];
    const float* W_ir     = (const float*)d_in[8];
    const float* b_ir     = (const float*)d_in[9];
    const float* W_iz     = (const float*)d_in[10];
    const float* b_iz     = (const float*)d_in[11];
    const float* W_in     = (const float*)d_in[12];
    const float* b_in     = (const float*)d_in[13];
    const float* W_hz     = (const float*)d_in[14];
    const float* b_hz     = (const float*)d_in[15];
    const float* W_hn     = (const float*)d_in[16];
    const float* b_hn     = (const float*)d_in[17];
    const float* W_out    = (const float*)d_in[18];
    const float* b_out    = (const float*)d_in[19];

    float* out = (float*)d_out;
    char*  ws  = (char*)d_ws;

    bf16*  h_prev_b = (bf16*)(ws + WS_HPREV_B);
    bf16*  h_new_b  = (bf16*)(ws + WS_HNEW_B);
    bf16*  xc_b     = (bf16*)(ws + WS_XC_B);
    bf16*  W1a_b    = (bf16*)(ws + WS_W1A_B);
    float* p_hB     = (float*)(ws + WS_P_HB);
    float* p_hz     = (float*)(ws + WS_P_HZ);
    float* p_hn     = (float*)(ws + WS_P_HN);
    float* p_iz     = (float*)(ws + WS_P_IZ);
    float* p_ir     = (float*)(ws + WS_P_IR);
    float* p_in     = (float*)(ws + WS_P_IN);
    float* scores_p = (float*)(ws + WS_SCORES);
    float* ctx_part = (float*)(ws + WS_CTX);
    bf16*  annb     = (bf16*)(ws + WS_ANNB);

    // 1) conversions + embedding gather
    k_prep<<<1088, 256, 0, stream>>>(x, h_prev, emb, attn_W1, h_prev_b, xc_b, W1a_b);
    k_convann<<<2048, 256, 0, stream>>>(ann, annb);

    // 2) hB / hz / hn  (h_prev @ {W1b, W_hz, W_hn}^T), split-K=4 partials
    {
        dim3 g(16, 4, 3);
        k_sgemm<<<g, 256, 0, stream>>>(h_prev_b, 1024, 256,
                                       attn_W1 + 1024, W_hz, W_hn, 2048, 1024, 1024,
                                       p_hB, p_hz, p_hn, nullptr, 1024, 0);
    }

    // 3) fused attention GEMM -> 16 score partials
    k_attn<<<2048, 256, 0, stream>>>(annb, W1a_b, p_hB, attn_b1, attn_W2, scores_p);

    // 4) softmax -> attention weights (final output region)
    k_softmax<<<64, 512, 0, stream>>>(scores_p, out + OUT_AW);

    // 5) context = sum_s aw * annb  (8 s-chunks)
    k_context<<<512, 256, 0, stream>>>(annb, out + OUT_AW, ctx_part);

    // 6) xc = [context, embed] in bf16
    k_xc<<<256, 256, 0, stream>>>(ctx_part, xc_b);

    // 7) gate GEMMs (xc @ {W_iz, W_ir, W_in}^T), K=2048, split-K=4
    {
        dim3 g(16, 4, 3);
        k_sgemm<<<g, 256, 0, stream>>>(xc_b, 2048, 512,
                                       W_iz, W_ir, W_in, 2048, 2048, 2048,
                                       p_iz, p_ir, p_in, nullptr, 1024, 0);
    }

    // 8) GRU elementwise -> h_new (f32 out + bf16 ws)
    k_gru<<<256, 256, 0, stream>>>(p_iz, p_ir, p_in, p_hz, p_hn,
                                   b_iz, b_ir, b_in, b_hz, b_hn,
                                   h_prev, out + OUT_HNEW, h_new_b);

    // 9) output logits = h_new @ W_out^T + b_out
    {
        dim3 g(500, 1, 1);
        k_sgemm<<<g, 256, 0, stream>>>(h_new_b, 1024, 1024,
                                       W_out, W_out, W_out, 1024, 1024, 1024,
                                       out + OUT_LOGITS, nullptr, nullptr,
                                       b_out, 32000, 1);
    }
}

// Round 3
// 173.602 us; speedup vs baseline: 1.2464x; 1.0712x over previous
//
#include <hip/hip_runtime.h>

// ---------------------------------------------------------------------------
// AttentionDecoder: B=64, S=512, H=1024, V=32000
// outputs (f32, concat): output [64,32000] | h_new [64,1024] | attn_w [64,512]
// ---------------------------------------------------------------------------

typedef __bf16 bf16;
typedef __attribute__((ext_vector_type(4))) float  f32x4;
typedef __attribute__((ext_vector_type(4))) float  fx4;
typedef __attribute__((ext_vector_type(8))) bf16   bf16x8;
typedef __attribute__((ext_vector_type(4))) bf16   bf16x4;
typedef __attribute__((ext_vector_type(4))) unsigned int u32x4;
typedef __attribute__((ext_vector_type(2))) unsigned int u32x2;

#define MFMA16x16x32(a, b, c) __builtin_amdgcn_mfma_f32_16x16x32_bf16(a, b, c, 0, 0, 0)

#define Bb   64
#define Ss   512
#define Hh   1024
#define Vv   32000
#define Mtot (Bb * Ss)          // 32768

// ---- d_ws layout (bytes) --------------------------------------------------
#define WS_HPREV_B   0                       // 64*1024 bf16   = 128KB
#define WS_HNEW_B    131072                  // 64*1024 bf16   = 128KB
#define WS_XC_B      262144                  // 64*2048 bf16   = 256KB
#define WS_W1A_B     524288                  // 1024*1024 bf16 = 2MB
#define WS_P_HB      2621440                 // [4][64][1024] f32 = 1MB
#define WS_P_HZ      3670016
#define WS_P_HN      4718592
#define WS_P_IZ      5767168
#define WS_P_IR      6815744
#define WS_P_IN      7864320
#define WS_SCORES    8912896                 // [16][32768] f32 = 2MB
#define WS_CTX       11010048                // [8][64][1024] f32 = 2MB
#define WS_ANNB      13107200                // 32768*1024 bf16 = 64MB
// total ~80.3MB

// ---- d_out offsets (floats) ----------------------------------------------
#define OUT_LOGITS   0
#define OUT_HNEW     2048000
#define OUT_AW       2113536

__device__ __forceinline__ float bf2f(unsigned short u) {
    unsigned int x = ((unsigned int)u) << 16;
    float f;
    __builtin_memcpy(&f, &x, 4);
    return f;
}

// async global->LDS, 16B per lane. LDS dest is wave-uniform base; HW writes
// base + lane*16.
__device__ __forceinline__ void gload_lds16(const bf16* g, bf16* l)
{
    __builtin_amdgcn_global_load_lds(
        (const __attribute__((address_space(1))) unsigned int*)g,
        (__attribute__((address_space(3))) unsigned int*)l,
        16, 0, 0);
}

// ===========================================================================
// k_prep: h_prev -> bf16 ; embed gather -> xc_b[:,H:2H] ; W1a -> bf16
// ===========================================================================
__global__ void k_prep(const int* __restrict__ x, const float* __restrict__ h_prev,
                       const float* __restrict__ emb, const float* __restrict__ attn_W1,
                       bf16* __restrict__ h_prev_b, bf16* __restrict__ xc_b,
                       bf16* __restrict__ W1a_b)
{
    int bid = blockIdx.x, t = threadIdx.x;
    if (bid < 64) {
        int b = bid;
        int row = x[b];
        for (int i = t; i < Hh; i += 256) {
            h_prev_b[b * Hh + i]          = (bf16)h_prev[b * Hh + i];
            xc_b[b * 2048 + Hh + i]       = (bf16)emb[(size_t)row * Hh + i];
        }
    } else {
        int row = bid - 64;                  // 0..1023 (one W1a row per block)
        int k4 = t * 4;
        fx4 v = *(const fx4*)(attn_W1 + (size_t)row * 2048 + k4);
        bf16x4 o;
#pragma unroll
        for (int q = 0; q < 4; q++) o[q] = (bf16)v[q];
        *(bf16x4*)(W1a_b + (size_t)row * Hh + k4) = o;
    }
}

// ===========================================================================
// k_convann: ann f32 -> bf16 (grid-stride, 8 elems/thread/iter)
// ===========================================================================
__global__ void k_convann(const float* __restrict__ ann, bf16* __restrict__ annb)
{
    size_t i = ((size_t)blockIdx.x * 256 + threadIdx.x) * 8;
    size_t stride = (size_t)gridDim.x * 256 * 8;
    size_t n = (size_t)Mtot * Hh;
    for (; i < n; i += stride) {
        fx4 v0 = *(const fx4*)(ann + i);
        fx4 v1 = *(const fx4*)(ann + i + 4);
        bf16x8 o;
#pragma unroll
        for (int q = 0; q < 4; q++) { o[q] = (bf16)v0[q]; o[q + 4] = (bf16)v1[q]; }
        *(bf16x8*)(annb + i) = o;
    }
}

// ===========================================================================
// k_sgemm: M=64 GEMM, out[m][n] = sum_k A_bf16[m][k] * (f32)Bmat[n][k]
// tile BM=64 BN=64 BK=64, 4 waves, dbuf reg-staged.
// ===========================================================================
__global__ __launch_bounds__(256, 2) void k_sgemm(
    const bf16* __restrict__ A, int lda, int kchunk,
    const float* __restrict__ B0, const float* __restrict__ B1, const float* __restrict__ B2,
    int ldb0, int ldb1, int ldb2,
    float* __restrict__ o0, float* __restrict__ o1, float* __restrict__ o2,
    const float* __restrict__ bias, int N, int finalOut)
{
    __shared__ __align__(16) bf16 lA[2][64][72];
    __shared__ __align__(16) bf16 lB[2][64][72];

    int nb = blockIdx.x, sk = blockIdx.y, mat = blockIdx.z;
    const float* Bp = (mat == 0) ? B0 : (mat == 1 ? B1 : B2);
    int ldb         = (mat == 0) ? ldb0 : (mat == 1 ? ldb1 : ldb2);
    float* op       = (mat == 0) ? o0 : (mat == 1 ? o1 : o2);

    int n0 = nb * 64, k0 = sk * kchunk;
    int t = threadIdx.x, lane = t & 63, wid = t >> 6;
    int srow = t >> 2, schunk = t & 3;

    const bf16*  agp = A  + (size_t)srow * lda + k0 + schunk * 16;
    const float* bgp = Bp + (size_t)(n0 + srow) * ldb + k0 + schunk * 16;

    f32x4 acc[4];
#pragma unroll
    for (int i = 0; i < 4; i++) acc[i] = (f32x4)0.0f;

    u32x4 aR0, aR1; fx4 bRf[4];
    int nk = kchunk >> 6;

    aR0 = *(const u32x4*)(agp);
    aR1 = *(const u32x4*)(agp + 8);
#pragma unroll
    for (int q = 0; q < 4; q++) bRf[q] = *(const fx4*)(bgp + q * 4);
    {
        *(u32x4*)&lA[0][srow][schunk * 16]     = aR0;
        *(u32x4*)&lA[0][srow][schunk * 16 + 8] = aR1;
        bf16x8 p0, p1;
#pragma unroll
        for (int q = 0; q < 4; q++) {
            p0[q] = (bf16)bRf[0][q]; p0[q + 4] = (bf16)bRf[1][q];
            p1[q] = (bf16)bRf[2][q]; p1[q + 4] = (bf16)bRf[3][q];
        }
        *(bf16x8*)&lB[0][srow][schunk * 16]     = p0;
        *(bf16x8*)&lB[0][srow][schunk * 16 + 8] = p1;
    }
    __syncthreads();

    int cur = 0;
    for (int ks = 0; ks < nk; ks++) {
        if (ks + 1 < nk) {
            aR0 = *(const u32x4*)(agp + (ks + 1) * 64);
            aR1 = *(const u32x4*)(agp + (ks + 1) * 64 + 8);
#pragma unroll
            for (int q = 0; q < 4; q++) bRf[q] = *(const fx4*)(bgp + (ks + 1) * 64 + q * 4);
        }
        int rA = lane & 15;
        int kc = (lane >> 4) * 8;
#pragma unroll
        for (int kk = 0; kk < 2; kk++) {
            bf16x8 bfr = *(bf16x8*)&lB[cur][wid * 16 + rA][kk * 32 + kc];
#pragma unroll
            for (int i = 0; i < 4; i++) {
                bf16x8 af = *(bf16x8*)&lA[cur][i * 16 + rA][kk * 32 + kc];
                acc[i] = MFMA16x16x32(af, bfr, acc[i]);
            }
        }
        if (ks + 1 < nk) {
            int nxt = cur ^ 1;
            *(u32x4*)&lA[nxt][srow][schunk * 16]     = aR0;
            *(u32x4*)&lA[nxt][srow][schunk * 16 + 8] = aR1;
            bf16x8 p0, p1;
#pragma unroll
            for (int q = 0; q < 4; q++) {
                p0[q] = (bf16)bRf[0][q]; p0[q + 4] = (bf16)bRf[1][q];
                p1[q] = (bf16)bRf[2][q]; p1[q + 4] = (bf16)bRf[3][q];
            }
            *(bf16x8*)&lB[nxt][srow][schunk * 16]     = p0;
            *(bf16x8*)&lB[nxt][srow][schunk * 16 + 8] = p1;
        }
        __syncthreads();
        cur ^= 1;
    }

    int n = n0 + wid * 16 + (lane & 15);
#pragma unroll
    for (int i = 0; i < 4; i++) {
#pragma unroll
        for (int r = 0; r < 4; r++) {
            int m = i * 16 + (lane >> 4) * 4 + r;
            float v = acc[i][r];
            if (finalOut) op[(size_t)m * N + n] = v + bias[n];
            else          op[(size_t)(sk * 64 + m) * N + n] = v;
        }
    }
}

// ===========================================================================
// k_attn v3: 256x256 tile, BK=64, 8 waves, counted-vmcnt 4-phase schedule.
// LDS 128KB dynamic: [buf2][mat2][half2][128 rows][64 k] bf16, 16KB halves.
// chunk-XOR swizzle c ^= (row&7) on both staging source and ds_read.
// Wave (wm=wid>>2, wn=wid&3): C rows wm*64+(i&3)*16 (+128 if i>=4),
// cols wn*32+(j&1)*16 (+128 if j>=2). Phase (a,ks): 16 MFMA.
// Staging: P0: A1(t+1), P1: B1(t+1) -> other buf; P3: A0(t+2)+B0(t+2) -> cur
// (after last reads). One vmcnt(4) per tile at P3.
// Fused epilogue: relu(hA+hB+b1)*W2 -> scores_part[nbp*4+wn][m].
// ===========================================================================
__global__ __launch_bounds__(512, 2) void k_attn(
    const bf16* __restrict__ annb, const bf16* __restrict__ Bw,
    const float* __restrict__ p_hB, const float* __restrict__ b1,
    const float* __restrict__ W2, float* __restrict__ scores_part)
{
    extern __shared__ char smem[];

    int bid = blockIdx.x;
    int wgid = (bid & 7) * 64 + (bid >> 3);       // XCD-contiguous (512%8==0)
    int mb = wgid >> 2, nbp = wgid & 3;

    int t = threadIdx.x, lane = t & 63, wid = t >> 6;
    int wm = wid >> 2, wn = wid & 3;
    int r = lane & 15, q = lane >> 4;

    // staging lane constants (linear LDS dest, inverse-swizzled source)
    int srow = t >> 3;                            // 0..63
    int gc   = (t & 7) ^ (srow & 7);
    size_t goff = (size_t)srow * 1024 + gc * 8;   // elems; +65536 for round 1
    int doff = wid * 1024;                        // bytes (+ lane*16 by HW)

    const bf16* aSrc = annb + (size_t)mb * 262144;   // 256 rows x 1024
    const bf16* bSrc = Bw   + (size_t)nbp * 262144;

    // ds_read lane constants
    int rowAoff = (wm * 64 + r) * 128;            // bytes within half
    int rowBoff = (wn * 32 + r) * 128;
    int e0 = (q ^ (r & 7)) * 16;                  // swizzled chunk, ks=0
    int e1 = e0 ^ 64;                             // ks=1

#define STAGEOP(src, half, buf, mat, kt) do {                                  \
        const bf16* s_ = (src) + (half) * 131072 + (size_t)(kt) * 64 + goff;   \
        char* d_ = smem + (buf) * 65536 + (mat) * 32768 + (half) * 16384 + doff; \
        gload_lds16(s_, (bf16*)d_);                                            \
        gload_lds16(s_ + 65536, (bf16*)(d_ + 8192));                           \
    } while (0)

#define VM4 asm volatile("s_waitcnt vmcnt(4)" ::: "memory")
#define VM0 asm volatile("s_waitcnt vmcnt(0)" ::: "memory")

    f32x4 acc[8][4];
#pragma unroll
    for (int i = 0; i < 8; i++)
#pragma unroll
        for (int j = 0; j < 4; j++) acc[i][j] = (f32x4)0.0f;

    bf16x8 bq[4];   // B frags for current ks, reused across the two A-halves

#define PH(AH, KS, READB, STG, ENDW) do {                                      \
        const char* pa_ = smem + cur * 65536 + (AH) * 16384 + rowAoff;         \
        bf16x8 aq[4];                                                          \
        _Pragma("unroll")                                                      \
        for (int ip = 0; ip < 4; ip++)                                         \
            aq[ip] = *(const bf16x8*)(pa_ + ip * 2048 + ((KS) ? e1 : e0));     \
        if (READB) {                                                           \
            _Pragma("unroll")                                                  \
            for (int jp = 0; jp < 4; jp++) {                                   \
                const char* pb_ = smem + cur * 65536 + 32768                   \
                                + (jp >> 1) * 16384 + rowBoff;                 \
                bq[jp] = *(const bf16x8*)(pb_ + (jp & 1) * 2048 + ((KS) ? e1 : e0)); \
            }                                                                  \
        }                                                                      \
        STG;                                                                   \
        __builtin_amdgcn_s_barrier();                                          \
        __builtin_amdgcn_s_setprio(1);                                         \
        _Pragma("unroll")                                                      \
        for (int ip = 0; ip < 4; ip++)                                         \
            _Pragma("unroll")                                                  \
            for (int jp = 0; jp < 4; jp++)                                     \
                acc[(AH) * 4 + ip][jp] =                                       \
                    MFMA16x16x32(aq[ip], bq[jp], acc[(AH) * 4 + ip][jp]);      \
        __builtin_amdgcn_s_setprio(0);                                         \
        ENDW;                                                                  \
        __builtin_amdgcn_s_barrier();                                          \
    } while (0)

#define TILE(tt, S1, S2, VMW)                                                  \
        PH(0, 0, 1, if (S1) STAGEOP(aSrc, 1, nxt, 0, (tt) + 1), );             \
        PH(1, 0, 0, if (S1) STAGEOP(bSrc, 1, nxt, 1, (tt) + 1), );             \
        PH(0, 1, 1, , );                                                       \
        PH(1, 1, 0, if (S2) { STAGEOP(aSrc, 0, cur, 0, (tt) + 2);              \
                              STAGEOP(bSrc, 0, cur, 1, (tt) + 2); }, VMW);

    // prologue: A0(0),B0(0),A1(0),B1(0) -> buf0 ; A0(1),B0(1) -> buf1
    STAGEOP(aSrc, 0, 0, 0, 0);
    STAGEOP(bSrc, 0, 0, 1, 0);
    STAGEOP(aSrc, 1, 0, 0, 0);
    STAGEOP(bSrc, 1, 0, 1, 0);
    STAGEOP(aSrc, 0, 1, 0, 1);
    STAGEOP(bSrc, 0, 1, 1, 1);
    VM4;
    __builtin_amdgcn_s_barrier();

#pragma unroll 1
    for (int kt = 0; kt < 14; kt++) {
        int cur = kt & 1, nxt = cur ^ 1;
        TILE(kt, 1, 1, VM4);
    }
    {   // kt = 14: stage tile 15 halves A1/B1; no t+2; drain before last tile
        int cur = 0, nxt = 1;
        TILE(14, 1, 0, VM0);
    }
    {   // kt = 15: all resident, no staging, no waits
        int cur = 1, nxt = 0;
        TILE(15, 0, 0, );
    }
#undef TILE
#undef PH
#undef STAGEOP

    // fused epilogue: relu(hA + hB + b1) * W2, reduce over this block's n
    int m0 = mb * 256, n0g = nbp * 256;
    int b = m0 >> 9;                               // single batch per block
    float hb[4], w2v[4];
#pragma unroll
    for (int j = 0; j < 4; j++) {
        int n = n0g + (j >> 1) * 128 + wn * 32 + (j & 1) * 16 + r;
        float h = p_hB[b * Hh + n] + p_hB[65536 + b * Hh + n]
                + p_hB[131072 + b * Hh + n] + p_hB[196608 + b * Hh + n];
        hb[j]  = h + b1[n];
        w2v[j] = W2[n];
    }
    float red[32];
#pragma unroll
    for (int i = 0; i < 8; i++)
#pragma unroll
        for (int rr = 0; rr < 4; rr++) {
            float s = 0.f;
#pragma unroll
            for (int j = 0; j < 4; j++) {
                float v = acc[i][j][rr] + hb[j];
                v = fmaxf(v, 0.f);
                s += v * w2v[j];
            }
            red[i * 4 + rr] = s;
        }
#pragma unroll
    for (int mask = 1; mask <= 8; mask <<= 1)
#pragma unroll
        for (int p = 0; p < 32; p++)
            red[p] += __shfl_xor(red[p], mask, 64);

    if (r == 0) {
        float* sp = scores_part + (size_t)(nbp * 4 + wn) * Mtot;
#pragma unroll
        for (int i = 0; i < 8; i++) {
            int m = m0 + wm * 64 + (i & 3) * 16 + (i >> 2) * 128 + q * 4;
#pragma unroll
            for (int rr = 0; rr < 4; rr++)
                sp[m + rr] = red[i * 4 + rr];
        }
    }
}

// ===========================================================================
// k_softmax: per b (64 blocks x 512 thr): sum 16 partials, softmax over s.
// ===========================================================================
__global__ void k_softmax(const float* __restrict__ scores_part, float* __restrict__ aw)
{
    int b = blockIdx.x, s = threadIdx.x;
    int lane = s & 63, wid = s >> 6;
    float v = 0.f;
#pragma unroll
    for (int p = 0; p < 16; p++) v += scores_part[(size_t)p * Mtot + b * Ss + s];

    __shared__ float redm[8], redsum[8];
    float m = v;
#pragma unroll
    for (int mask = 32; mask; mask >>= 1) m = fmaxf(m, __shfl_xor(m, mask, 64));
    if (lane == 0) redm[wid] = m;
    __syncthreads();
    float bm = redm[0];
#pragma unroll
    for (int w = 1; w < 8; w++) bm = fmaxf(bm, redm[w]);

    float e = expf(v - bm);
    float ss = e;
#pragma unroll
    for (int mask = 32; mask; mask >>= 1) ss += __shfl_xor(ss, mask, 64);
    if (lane == 0) redsum[wid] = ss;
    __syncthreads();
    float tot = 0.f;
#pragma unroll
    for (int w = 0; w < 8; w++) tot += redsum[w];

    aw[b * Ss + s] = e / tot;
}

// ===========================================================================
// k_context: ctx_part[sc][b][h] = sum_{s in 64-chunk} aw[b,s]*annb[b,s,h]
// ===========================================================================
__global__ void k_context(const bf16* __restrict__ annb, const float* __restrict__ aw,
                          float* __restrict__ ctx_part)
{
    __shared__ float law[64];
    int bid = blockIdx.x;
    int b = bid >> 3, sc = bid & 7;
    int t = threadIdx.x;
    if (t < 64) law[t] = aw[b * Ss + sc * 64 + t];
    __syncthreads();
    int h0 = t * 4;
    const bf16* ap = annb + (size_t)(b * Ss + sc * 64) * Hh + h0;
    float a0 = 0, a1 = 0, a2 = 0, a3 = 0;
#pragma unroll 4
    for (int s2 = 0; s2 < 64; s2++) {
        float w = law[s2];
        u32x2 v = *(const u32x2*)(ap + (size_t)s2 * Hh);
        a0 += w * bf2f((unsigned short)(v[0] & 0xffff));
        a1 += w * bf2f((unsigned short)(v[0] >> 16));
        a2 += w * bf2f((unsigned short)(v[1] & 0xffff));
        a3 += w * bf2f((unsigned short)(v[1] >> 16));
    }
    fx4 o; o[0] = a0; o[1] = a1; o[2] = a2; o[3] = a3;
    *(fx4*)(ctx_part + sc * 65536 + b * Hh + h0) = o;
}

// ===========================================================================
// k_xc: xc_b[:, 0:H] = bf16(sum of 8 ctx partials)
// ===========================================================================
__global__ void k_xc(const float* __restrict__ ctx_part, bf16* __restrict__ xc_b)
{
    int idx = blockIdx.x * 256 + threadIdx.x;          // 65536
    float c = 0.f;
#pragma unroll
    for (int p = 0; p < 8; p++) c += ctx_part[p * 65536 + idx];
    int b = idx >> 10, h = idx & 1023;
    xc_b[b * 2048 + h] = (bf16)c;
}

// ===========================================================================
// k_gru: gates + h_new (reads 4-way split-K partials)
// ===========================================================================
__global__ void k_gru(const float* __restrict__ p_iz, const float* __restrict__ p_ir,
                      const float* __restrict__ p_in, const float* __restrict__ p_hz,
                      const float* __restrict__ p_hn,
                      const float* __restrict__ b_iz, const float* __restrict__ b_ir,
                      const float* __restrict__ b_in, const float* __restrict__ b_hz,
                      const float* __restrict__ b_hn,
                      const float* __restrict__ h_prev,
                      float* __restrict__ out_h, bf16* __restrict__ h_new_b)
{
    int idx = blockIdx.x * 256 + threadIdx.x;          // 65536
    int o = idx & 1023;
    float iz = p_iz[idx] + p_iz[65536 + idx] + p_iz[131072 + idx] + p_iz[196608 + idx];
    float ir = p_ir[idx] + p_ir[65536 + idx] + p_ir[131072 + idx] + p_ir[196608 + idx];
    float in_ = p_in[idx] + p_in[65536 + idx] + p_in[131072 + idx] + p_in[196608 + idx];
    float hz = p_hz[idx] + p_hz[65536 + idx] + p_hz[131072 + idx] + p_hz[196608 + idx];
    float hn = p_hn[idx] + p_hn[65536 + idx] + p_hn[131072 + idx] + p_hn[196608 + idx];
    hz += b_hz[o];
    hn += b_hn[o];
    float z = 1.f / (1.f + expf(-(iz + b_iz[o] + hz)));
    float r = 1.f / (1.f + expf(-(ir + b_ir[o] + hz)));
    float g = tanhf(in_ + b_in[o] + r * hn);
    float hp = h_prev[idx];
    float hnew = (1.f - z) * g + z * hp;
    out_h[idx] = hnew;
    h_new_b[idx] = (bf16)hnew;
}

// ===========================================================================
extern "C" void kernel_launch(void* const* d_in, const int* in_sizes, int n_in,
                              void* d_out, int out_size, void* d_ws, size_t ws_size,
                              hipStream_t stream)
{
    const int*   x        = (const int*)d_in[0];
    const float* h_prev   = (const float*)d_in[1];
    const float* ann      = (const float*)d_in[2];
    const float* emb      = (const float*)d_in[3];
    const float* attn_W1  = (const float*)d_in[4];
    const float* attn_b1  = (const float*)d_in[5];
    const float* attn_W2  = (const float*)d_in[6];
    const float* W_ir     = (const float*)d_in[8];
    const float* b_ir     = (const float*)d_in[9];
    const float* W_iz     = (const float*)d_in[10];
    const float* b_iz     = (const float*)d_in[11];
    const float* W_in     = (const float*)d_in[12];
    const float* b_in     = (const float*)d_in[13];
    const float* W_hz     = (const float*)d_in[14];
    const float* b_hz     = (const float*)d_in[15];
    const float* W_hn     = (const float*)d_in[16];
    const float* b_hn     = (const float*)d_in[17];
    const float* W_out    = (const float*)d_in[18];
    const float* b_out    = (const float*)d_in[19];

    float* out = (float*)d_out;
    char*  ws  = (char*)d_ws;

    bf16*  h_prev_b = (bf16*)(ws + WS_HPREV_B);
    bf16*  h_new_b  = (bf16*)(ws + WS_HNEW_B);
    bf16*  xc_b     = (bf16*)(ws + WS_XC_B);
    bf16*  W1a_b    = (bf16*)(ws + WS_W1A_B);
    float* p_hB     = (float*)(ws + WS_P_HB);
    float* p_hz     = (float*)(ws + WS_P_HZ);
    float* p_hn     = (float*)(ws + WS_P_HN);
    float* p_iz     = (float*)(ws + WS_P_IZ);
    float* p_ir     = (float*)(ws + WS_P_IR);
    float* p_in     = (float*)(ws + WS_P_IN);
    float* scores_p = (float*)(ws + WS_SCORES);
    float* ctx_part = (float*)(ws + WS_CTX);
    bf16*  annb     = (bf16*)(ws + WS_ANNB);

    // allow 128KB dynamic LDS for k_attn (idempotent, no stream op)
    hipFuncSetAttribute(reinterpret_cast<const void*>(k_attn),
                        hipFuncAttributeMaxDynamicSharedMemorySize, 131072);

    // 1) conversions + embedding gather
    k_prep<<<1088, 256, 0, stream>>>(x, h_prev, emb, attn_W1, h_prev_b, xc_b, W1a_b);
    k_convann<<<2048, 256, 0, stream>>>(ann, annb);

    // 2) hB / hz / hn  (h_prev @ {W1b, W_hz, W_hn}^T), split-K=4 partials
    {
        dim3 g(16, 4, 3);
        k_sgemm<<<g, 256, 0, stream>>>(h_prev_b, 1024, 256,
                                       attn_W1 + 1024, W_hz, W_hn, 2048, 1024, 1024,
                                       p_hB, p_hz, p_hn, nullptr, 1024, 0);
    }

    // 3) fused attention GEMM -> 16 score partials
    k_attn<<<512, 512, 131072, stream>>>(annb, W1a_b, p_hB, attn_b1, attn_W2, scores_p);

    // 4) softmax -> attention weights (final output region)
    k_softmax<<<64, 512, 0, stream>>>(scores_p, out + OUT_AW);

    // 5) context = sum_s aw * annb  (8 s-chunks)
    k_context<<<512, 256, 0, stream>>>(annb, out + OUT_AW, ctx_part);

    // 6) xc = [context, embed] in bf16
    k_xc<<<256, 256, 0, stream>>>(ctx_part, xc_b);

    // 7) gate GEMMs (xc @ {W_iz, W_ir, W_in}^T), K=2048, split-K=4
    {
        dim3 g(16, 4, 3);
        k_sgemm<<<g, 256, 0, stream>>>(xc_b, 2048, 512,
                                       W_iz, W_ir, W_in, 2048, 2048, 2048,
                                       p_iz, p_ir, p_in, nullptr, 1024, 0);
    }

    // 8) GRU elementwise -> h_new (f32 out + bf16 ws)
    k_gru<<<256, 256, 0, stream>>>(p_iz, p_ir, p_in, p_hz, p_hn,
                                   b_iz, b_ir, b_in, b_hz, b_hn,
                                   h_prev, out + OUT_HNEW, h_new_b);

    // 9) output logits = h_new @ W_out^T + b_out
    {
        dim3 g(500, 1, 1);
        k_sgemm<<<g, 256, 0, stream>>>(h_new_b, 1024, 1024,
                                       W_out, W_out, W_out, 1024, 1024, 1024,
                                       out + OUT_LOGITS, nullptr, nullptr,
                                       b_out, 32000, 1);
    }
}